// Round 3
// baseline (426.575 us; speedup 1.0000x reference)
//
#include <hip/hip_runtime.h>

// MaxUnpooling2D: out = zeros(8*256*256*64); out[idx + batch*2^22] += in
//   inputs/indices: (8, 128, 128, 64) -> 2^23 elements, 2^21 float4/int4 packets
//   output:         (8, 256, 256, 64) -> 2^25 floats (128 MiB), per_batch_out = 2^22
//
// R2 change: XCD-pinned batches + workgroup-scope HW atomics.
// Evidence from R1: WRITE_SIZE == 8.4M x 32B exactly -> every device-scope
// atomicAdd is forwarded past the per-XCD L2 as an individual 32B fabric
// transaction (the cross-XCD coherence point is the bottleneck, ~20.7 G/s;
// HBM 8%, VALU 0.3%). Fix: batch b's blocks are pinned to XCD b via the
// measured round-robin mapping (xcd == blockIdx.x % 8); each batch's output
// slice (16 MiB, line-aligned) is then written by exactly one XCD, so a
// workgroup-scope atomic (global_atomic_add_f32 without sc1 -> executes in
// the local XCD L2, lines coalesce and write back once) is sufficient.

__global__ __launch_bounds__(256) void maxunpool_scatter_xcd(
    const float4* __restrict__ in4,
    const int4*  __restrict__ idx4,
    float* __restrict__ out,
    int packets_per_batch)
{
    const int batch = blockIdx.x & 7;      // == XCD id (measured round-robin)
    const int sub   = blockIdx.x >> 3;
    const int p     = sub * blockDim.x + threadIdx.x;
    if (p >= packets_per_batch) return;

    const int t = batch * packets_per_batch + p;   // coalesced within each wave
    float4 v = in4[t];
    int4  ix = idx4[t];

    float* base = out + ((size_t)batch << 22);
    __hip_atomic_fetch_add(base + ix.x, v.x, __ATOMIC_RELAXED, __HIP_MEMORY_SCOPE_WORKGROUP);
    __hip_atomic_fetch_add(base + ix.y, v.y, __ATOMIC_RELAXED, __HIP_MEMORY_SCOPE_WORKGROUP);
    __hip_atomic_fetch_add(base + ix.z, v.z, __ATOMIC_RELAXED, __HIP_MEMORY_SCOPE_WORKGROUP);
    __hip_atomic_fetch_add(base + ix.w, v.w, __ATOMIC_RELAXED, __HIP_MEMORY_SCOPE_WORKGROUP);
}

extern "C" void kernel_launch(void* const* d_in, const int* in_sizes, int n_in,
                              void* d_out, int out_size, void* d_ws, size_t ws_size,
                              hipStream_t stream) {
    const float* inputs  = (const float*)d_in[0];
    const int*   indices = (const int*)d_in[1];
    float*       out     = (float*)d_out;

    const int n   = in_sizes[0];          // 8,388,608
    const int n4  = n >> 2;               // 2,097,152 packets
    const int ppb = n4 >> 3;              // 262,144 packets per batch

    // Output must be zeroed every call (harness poisons once, never re-poisons).
    hipMemsetAsync(d_out, 0, (size_t)out_size * sizeof(float), stream);

    const int block = 256;
    const int blocks_per_batch = (ppb + block - 1) / block;   // 1024
    const int grid = 8 * blocks_per_batch;                    // 8192

    maxunpool_scatter_xcd<<<grid, block, 0, stream>>>(
        (const float4*)inputs, (const int4*)indices, out, ppb);
}

// Round 4
// 128.796 us; speedup vs baseline: 3.3120x; 3.3120x over previous
//
#include <hip/hip_runtime.h>

// MaxUnpooling2D: out = zeros(8*256*256*64); out[idx + batch*2^22] += in
//   inputs/indices: (8,128,128,64) -> 2^23 elements; output: (8,256,256,64) -> 2^25 floats
//
// R3: global fp32 atomics hit a hard wall on gfx950: WRITE_SIZE == count*32B
// exactly, rate == ~1 atomic/cycle/XCD (20.7 G/s -> 405 us), independent of
// scope/occupancy. So: two-phase binning. Phase 1 bins (loc,val) pairs into
// 2048 buckets (one 16K-float output tile each) using an LDS histogram +
// ONE global int atomic per (block,bucket) to reserve slots. Phase 2: each
// block accumulates its bucket in a 64 KiB LDS tile (LDS atomics) and writes
// the tile densely -- also covers the zeroing, so no output memset. Phase 3
// drains the (statistically empty) overflow list.

#define NBUCKETS     2048
#define BUCKET_SHIFT 14                 // 16384 floats per bucket
#define BUCKET_MASK  16383
#define CAP          5120               // mean 4096, sigma 64 -> +16 sigma
#define EPB          32768              // elements per phase-1 block
#define OVF_CAP      65536

// d_ws layout:
//   [0,      8192)  counts[2048] (int)
//   [8192,   8196)  ovf_count (int)
//   [16384,  16384 + 2048*5120*8)  pairs  (int2: {loc14, val bits})
//   [PAIRS_END, +OVF_CAP*8)        ovf_pairs (int2: {global25, val bits})
#define PAIRS_OFF  16384
#define PAIRS_BYTES ((size_t)NBUCKETS * CAP * 8)
#define OVF_OFF    (PAIRS_OFF + PAIRS_BYTES)
#define WS_NEEDED  (OVF_OFF + (size_t)OVF_CAP * 8)

__global__ __launch_bounds__(512) void p1_bin(const int* __restrict__ idx,
                                              const float* __restrict__ val,
                                              int* __restrict__ counts,
                                              int2* __restrict__ pairs,
                                              int* __restrict__ ovf_cnt,
                                              int2* __restrict__ ovf_pairs)
{
    __shared__ int hist[NBUCKETS];
    __shared__ int base[NBUCKETS];
    const int tid = threadIdx.x;
    const int blk_base = blockIdx.x * EPB;            // fits int (<= 8.4M)
    const int batch_hi = (blk_base >> 20) << 8;       // batch*2^22 >> 14

    for (int i = tid; i < NBUCKETS; i += 512) hist[i] = 0;
    __syncthreads();

    const int4* idx4 = (const int4*)(idx + blk_base);
    const int npk = EPB / 4;                          // 8192 int4 packets

    // pass A: block-local histogram (LDS atomics)
    for (int p = tid; p < npk; p += 512) {
        int4 v = idx4[p];
        atomicAdd(&hist[batch_hi | (v.x >> BUCKET_SHIFT)], 1);
        atomicAdd(&hist[batch_hi | (v.y >> BUCKET_SHIFT)], 1);
        atomicAdd(&hist[batch_hi | (v.z >> BUCKET_SHIFT)], 1);
        atomicAdd(&hist[batch_hi | (v.w >> BUCKET_SHIFT)], 1);
    }
    __syncthreads();

    // reserve contiguous chunks: one global int atomic per (block,bucket)
    for (int i = tid; i < NBUCKETS; i += 512) {
        int c = hist[i];
        base[i] = c ? atomicAdd(&counts[i], c) : 0;
        hist[i] = 0;                                  // reuse as cursor
    }
    __syncthreads();

    // pass B: scatter pairs into reserved chunks (plain 8B stores)
    const float4* val4 = (const float4*)(val + blk_base);
    for (int p = tid; p < npk; p += 512) {
        int4   ix = idx4[p];
        float4 v  = val4[p];
        #pragma unroll
        for (int c = 0; c < 4; ++c) {
            int  i1 = (c == 0) ? ix.x : (c == 1) ? ix.y : (c == 2) ? ix.z : ix.w;
            float f = (c == 0) ? v.x  : (c == 1) ? v.y  : (c == 2) ? v.z  : v.w;
            int b   = batch_hi | (i1 >> BUCKET_SHIFT);
            int cur = atomicAdd(&hist[b], 1);
            int off = base[b] + cur;
            int2 pr;
            pr.y = __float_as_int(f);
            if (off < CAP) {
                pr.x = i1 & BUCKET_MASK;
                pairs[(size_t)b * CAP + off] = pr;
            } else {
                int o = atomicAdd(ovf_cnt, 1);
                if (o < OVF_CAP) {
                    pr.x = (b << BUCKET_SHIFT) | (i1 & BUCKET_MASK); // global out idx
                    ovf_pairs[o] = pr;
                }
            }
        }
    }
}

__global__ __launch_bounds__(256) void p2_acc(const int* __restrict__ counts,
                                              const int2* __restrict__ pairs,
                                              float* __restrict__ out)
{
    __shared__ float acc[1 << BUCKET_SHIFT];          // 64 KiB
    const int b = blockIdx.x;

    float4* acc4 = (float4*)acc;
    for (int i = threadIdx.x; i < (1 << BUCKET_SHIFT) / 4; i += 256)
        acc4[i] = float4{0.f, 0.f, 0.f, 0.f};
    __syncthreads();

    int n = counts[b];
    if (n > CAP) n = CAP;
    const int2* pb = pairs + (size_t)b * CAP;
    for (int i = threadIdx.x; i < n; i += 256) {
        int2 pr = pb[i];
        atomicAdd(&acc[pr.x], __int_as_float(pr.y));  // LDS atomic
    }
    __syncthreads();

    float4* out4 = (float4*)(out + ((size_t)b << BUCKET_SHIFT));
    for (int i = threadIdx.x; i < (1 << BUCKET_SHIFT) / 4; i += 256)
        out4[i] = acc4[i];
}

__global__ void p3_ovf(const int* __restrict__ ovf_cnt,
                       const int2* __restrict__ ovf_pairs,
                       float* __restrict__ out)
{
    int n = *ovf_cnt;
    if (n > OVF_CAP) n = OVF_CAP;
    const int stride = gridDim.x * blockDim.x;
    for (int i = blockIdx.x * blockDim.x + threadIdx.x; i < n; i += stride) {
        int2 pr = ovf_pairs[i];
        atomicAdd(&out[pr.x], __int_as_float(pr.y));
    }
}

// fallback (R1 path) if workspace is too small
__global__ void maxunpool_scatter_fb(const float4* __restrict__ in4,
                                     const int4* __restrict__ idx4,
                                     float* __restrict__ out, int n4)
{
    const int t = blockIdx.x * blockDim.x + threadIdx.x;
    if (t >= n4) return;
    float4 v = in4[t];
    int4  ix = idx4[t];
    const int boff = (t >> 18) << 22;
    atomicAdd(out + boff + ix.x, v.x);
    atomicAdd(out + boff + ix.y, v.y);
    atomicAdd(out + boff + ix.z, v.z);
    atomicAdd(out + boff + ix.w, v.w);
}

extern "C" void kernel_launch(void* const* d_in, const int* in_sizes, int n_in,
                              void* d_out, int out_size, void* d_ws, size_t ws_size,
                              hipStream_t stream) {
    const float* inputs  = (const float*)d_in[0];
    const int*   indices = (const int*)d_in[1];
    float*       out     = (float*)d_out;
    const int n = in_sizes[0];                        // 8,388,608

    if (ws_size < WS_NEEDED || n != (8 << 20)) {
        // fallback: device-atomic scatter (405 us)
        hipMemsetAsync(d_out, 0, (size_t)out_size * sizeof(float), stream);
        const int n4 = n >> 2;
        maxunpool_scatter_fb<<<(n4 + 255) / 256, 256, 0, stream>>>(
            (const float4*)inputs, (const int4*)indices, out, n4);
        return;
    }

    char* ws        = (char*)d_ws;
    int*  counts    = (int*)ws;
    int*  ovf_cnt   = (int*)(ws + 8192);
    int2* pairs     = (int2*)(ws + PAIRS_OFF);
    int2* ovf_pairs = (int2*)(ws + OVF_OFF);

    // zero counters + overflow counter each call
    hipMemsetAsync(ws, 0, 8196, stream);

    const int p1_blocks = n / EPB;                    // 256
    p1_bin<<<p1_blocks, 512, 0, stream>>>(indices, inputs, counts, pairs,
                                          ovf_cnt, ovf_pairs);
    p2_acc<<<NBUCKETS, 256, 0, stream>>>(counts, pairs, out);
    p3_ovf<<<16, 256, 0, stream>>>(ovf_cnt, ovf_pairs, out);
}